// Round 3
// baseline (473.116 us; speedup 1.0000x reference)
//
#include <hip/hip_runtime.h>

#define NB 262144
#define AA 10
#define DD 10
#define KK 32

typedef float v2f __attribute__((ext_vector_type(2)));
typedef unsigned int uint32;

// ---- helpers ----------------------------------------------------------------
static __device__ __forceinline__ v2f mk2(float a, float b) {
    v2f r; r.x = a; r.y = b; return r;
}
static __device__ __forceinline__ float b2f(unsigned short h) {
    union { uint32 u; float f; } c; c.u = ((uint32)h) << 16; return c.f;
}
static __device__ __forceinline__ float bflo(uint32 w) {
    union { uint32 u; float f; } c; c.u = w << 16; return c.f;
}
static __device__ __forceinline__ float bfhi(uint32 w) {
    union { uint32 u; float f; } c; c.u = w & 0xffff0000u; return c.f;
}
// pack two f32 -> one reg of two bf16 (only used on the f32-input fallback path)
static __device__ __forceinline__ uint32 cvtpk(float lo, float hi) {
    uint32 d; asm("v_cvt_pk_bf16_f32 %0, %1, %2" : "=v"(d) : "v"(lo), "v"(hi)); return d;
}

// f32-vs-bf16 detection by exponent-field statistics (verified earlier rounds).
__device__ __forceinline__ int detect_f32(const unsigned short* p, int nshorts,
                                          unsigned expthr, int lane) {
    int bad = 0;
    if (lane < nshorts) {
        unsigned e = (p[lane] >> 7) & 0xFFu;
        bad = (e >= expthr);
    }
    return __any(bad);
}

// ---- prep: convert + pack weights into workspace ----------------------------
// wf layout (floats):
//   [0:100)            M row-major
//   [128 + k*24)       user row k: Pu[k][0..9] | Pi[k][0..9] | pu[k] | pad3
//   [896 + k*24)       item row k: Pi[k][0..9] | Pu[k][0..9] | pi[k] | pad3
__global__ __launch_bounds__(64) void prep_weights(
    const unsigned short* __restrict__ wM,
    const unsigned short* __restrict__ wPu,
    const unsigned short* __restrict__ wpu,
    const unsigned short* __restrict__ wPi,
    const unsigned short* __restrict__ wpi,
    float* __restrict__ wf)
{
    const int t = threadIdx.x;
    int f = 0;
    f |= detect_f32(wM,  64, 125, t) << 0;
    f |= detect_f32(wPu, 64, 125, t) << 1;
    f |= detect_f32(wpu, 32, 125, t) << 2;
    f |= detect_f32(wPi, 64, 125, t) << 3;
    f |= detect_f32(wpi, 32, 125, t) << 4;
    const float* fM  = (const float*)wM;
    const float* fPu = (const float*)wPu;
    const float* fpu = (const float*)wpu;
    const float* fPi = (const float*)wPi;
    const float* fpi = (const float*)wpi;

    for (int i = t; i < 128; i += 64) wf[i] = (i < 100) ? ((f & 1) ? fM[i] : b2f(wM[i])) : 0.f;

    for (int i = t; i < KK * 24; i += 64) {
        const int k = i / 24, j = i % 24;
        float vu = 0.f, vi = 0.f;
        if (j < 10) {
            vu = (f & 2) ? fPu[k * 10 + j] : b2f(wPu[k * 10 + j]);
            vi = (f & 8) ? fPi[k * 10 + j] : b2f(wPi[k * 10 + j]);
        } else if (j < 20) {
            vu = (f & 8) ? fPi[k * 10 + j - 10] : b2f(wPi[k * 10 + j - 10]);
            vi = (f & 2) ? fPu[k * 10 + j - 10] : b2f(wPu[k * 10 + j - 10]);
        } else if (j == 20) {
            vu = (f & 4)  ? fpu[k] : b2f(wpu[k]);
            vi = (f & 16) ? fpi[k] : b2f(wpi[k]);
        }
        wf[128 + i] = vu;
        wf[896 + i] = vi;
    }
}

// ---- main kernel -------------------------------------------------------------
// One thread per batch. Register plan (bf16 inputs, the measured case):
//   V2 f32 (100) + X2 f32 (100, born in user pass) + Upk bf16 (50, decays)
//   + per-u temps (~35)  ->  peak ~285, small AGPR tail, no scratch.
// Dataflow (single pass over u computes aff ONCE):
//   per u: expand U[u]; um = U[u]*M (LDS broadcast reads);
//          per v: r = relu(um*V[v]);  Wr += r*V[v];  X[v] += r*U[u];
//          user k-loop (rolled, unroll 2; weights from LDS broadcast)
//   user softmax/store;  per v: item k-loop over [V[v] | X[v]];  softmax/store.
__global__ __launch_bounds__(64, 2) void aie_main(
    const unsigned short* __restrict__ user_rep,
    const unsigned short* __restrict__ item_rep,
    const float* __restrict__ wf,
    float* __restrict__ out)
{
    __shared__ float swt[1664];   // 6.7 KB: M + both packed weight-row blocks
    const int t = threadIdx.x;
    const long long b = (long long)blockIdx.x * 64 + t;

    // stage weights to LDS (coalesced float4)
    {
        const float4* s = (const float4*)wf;
        float4* d4 = (float4*)swt;
        #pragma unroll
        for (int i = 0; i < 7; i++) {
            int idx = t + 64 * i;
            if (idx < 416) d4[idx] = s[idx];
        }
    }

    const int fu = detect_f32(user_rep, 64, 137, t);
    const int fi = detect_f32(item_rep, 64, 137, t);

    // ---- load inputs as packed bf16 pairs (exact when inputs are bf16) ----
    uint32 Vpk[50], Upk[50];
    if (!fi) {
        const uint2* g = (const uint2*)(item_rep + b * 100);
        #pragma unroll
        for (int j = 0; j < 25; j++) { uint2 w = g[j]; Vpk[2 * j] = w.x; Vpk[2 * j + 1] = w.y; }
    } else {
        const float4* g = (const float4*)((const float*)item_rep + b * 100);
        #pragma unroll
        for (int j = 0; j < 25; j++) { float4 w = g[j]; Vpk[2 * j] = cvtpk(w.x, w.y); Vpk[2 * j + 1] = cvtpk(w.z, w.w); }
    }
    if (!fu) {
        const uint2* g = (const uint2*)(user_rep + b * 100);
        #pragma unroll
        for (int j = 0; j < 25; j++) { uint2 w = g[j]; Upk[2 * j] = w.x; Upk[2 * j + 1] = w.y; }
    } else {
        const float4* g = (const float4*)((const float*)user_rep + b * 100);
        #pragma unroll
        for (int j = 0; j < 25; j++) { float4 w = g[j]; Upk[2 * j] = cvtpk(w.x, w.y); Upk[2 * j + 1] = cvtpk(w.z, w.w); }
    }

    // ---- unpack V to f32 (V is read ~30x per u: keep hot in f32) ----
    v2f V2[AA][5];
    #pragma unroll
    for (int p = 0; p < 50; p++) V2[p / 5][p % 5] = mk2(bflo(Vpk[p]), bfhi(Vpk[p]));

    __syncthreads();   // weight LDS ready

    v2f X2[AA][5];     // born during u==0 iteration
    float us[AA];

    // =================== fused user pass (aff computed once) ===================
    #pragma unroll
    for (int u = 0; u < AA; u++) {
        asm volatile("" ::: "memory");   // stop cross-u CSE of LDS weight reads

        v2f Uu[5];
        #pragma unroll
        for (int j = 0; j < 5; j++) Uu[j] = mk2(bflo(Upk[u * 5 + j]), bfhi(Upk[u * 5 + j]));

        // um = U[u] * M   (5 e-pairs; M rows broadcast from LDS)
        v2f um2[5];
        {
            const float x = Uu[0].x;
            #pragma unroll
            for (int j = 0; j < 5; j++) um2[j] = x * mk2(swt[2 * j], swt[2 * j + 1]);
        }
        #pragma unroll
        for (int d = 1; d < DD; d++) {
            const float x = (d & 1) ? Uu[d >> 1].y : Uu[d >> 1].x;
            #pragma unroll
            for (int j = 0; j < 5; j++)
                um2[j] += x * mk2(swt[d * 10 + 2 * j], swt[d * 10 + 2 * j + 1]);
        }

        // aff row -> Wr (for user branch) and X accumulation (for item branch)
        v2f Wr[5];
        #pragma unroll
        for (int j = 0; j < 5; j++) Wr[j] = mk2(0.f, 0.f);
        #pragma unroll
        for (int v = 0; v < AA; v++) {
            v2f r2 = um2[0] * V2[v][0];
            #pragma unroll
            for (int j = 1; j < 5; j++) r2 += um2[j] * V2[v][j];
            const float r = fmaxf(r2.x + r2.y, 0.f);
            #pragma unroll
            for (int j = 0; j < 5; j++) Wr[j] += r * V2[v][j];
            if (u == 0) {
                #pragma unroll
                for (int j = 0; j < 5; j++) X2[v][j] = r * Uu[j];
            } else {
                #pragma unroll
                for (int j = 0; j < 5; j++) X2[v][j] += r * Uu[j];
            }
        }

        // user k-loop: weights broadcast from LDS, rolled (tiny I-footprint)
        float acc = 0.f;
        #pragma unroll 2
        for (int k = 0; k < KK; k++) {
            const int o = 128 + k * 24;
            v2f a = mk2(swt[o],      swt[o + 1])  * Uu[0];
            v2f c = mk2(swt[o + 10], swt[o + 11]) * Wr[0];
            #pragma unroll
            for (int j = 1; j < 5; j++) {
                a += mk2(swt[o + 2 * j],      swt[o + 2 * j + 1])      * Uu[j];
                c += mk2(swt[o + 10 + 2 * j], swt[o + 10 + 2 * j + 1]) * Wr[j];
            }
            v2f s = a + c;
            acc += swt[o + 20] * fmaxf(s.x + s.y, 0.f);
        }
        us[u] = acc;
    }

    // ---- user softmax + direct stores ----
    {
        float mx = us[0];
        #pragma unroll
        for (int u = 1; u < AA; u++) mx = fmaxf(mx, us[u]);
        float s = 0.f;
        #pragma unroll
        for (int u = 0; u < AA; u++) { us[u] = __expf(us[u] - mx); s += us[u]; }
        const float inv = 1.f / s;
        float* o0 = out + b * 10;
        #pragma unroll
        for (int j = 0; j < 5; j++)
            *(float2*)(o0 + 2 * j) = make_float2(us[2 * j] * inv, us[2 * j + 1] * inv);
    }

    // =================== item pass: k-loops over [V[v] | X[v]] ===================
    float isc[AA];
    #pragma unroll
    for (int v = 0; v < AA; v++) {
        asm volatile("" ::: "memory");
        float acc = 0.f;
        #pragma unroll 2
        for (int k = 0; k < KK; k++) {
            const int o = 896 + k * 24;
            v2f a = mk2(swt[o],      swt[o + 1])  * V2[v][0];
            v2f c = mk2(swt[o + 10], swt[o + 11]) * X2[v][0];
            #pragma unroll
            for (int j = 1; j < 5; j++) {
                a += mk2(swt[o + 2 * j],      swt[o + 2 * j + 1])      * V2[v][j];
                c += mk2(swt[o + 10 + 2 * j], swt[o + 10 + 2 * j + 1]) * X2[v][j];
            }
            v2f s = a + c;
            acc += swt[o + 20] * fmaxf(s.x + s.y, 0.f);
        }
        isc[v] = acc;
    }

    // ---- item softmax + direct stores ----
    {
        float mx = isc[0];
        #pragma unroll
        for (int v = 1; v < AA; v++) mx = fmaxf(mx, isc[v]);
        float s = 0.f;
        #pragma unroll
        for (int v = 0; v < AA; v++) { isc[v] = __expf(isc[v] - mx); s += isc[v]; }
        const float inv = 1.f / s;
        float* o1 = out + (size_t)NB * 10 + b * 10;
        #pragma unroll
        for (int j = 0; j < 5; j++)
            *(float2*)(o1 + 2 * j) = make_float2(isc[2 * j] * inv, isc[2 * j + 1] * inv);
    }
}

extern "C" void kernel_launch(void* const* d_in, const int* in_sizes, int n_in,
                              void* d_out, int out_size, void* d_ws, size_t ws_size,
                              hipStream_t stream) {
    const unsigned short* user_rep = (const unsigned short*)d_in[0];
    const unsigned short* item_rep = (const unsigned short*)d_in[1];
    float* wf = (float*)d_ws;

    hipLaunchKernelGGL(prep_weights, dim3(1), dim3(64), 0, stream,
                       (const unsigned short*)d_in[2], (const unsigned short*)d_in[3],
                       (const unsigned short*)d_in[4], (const unsigned short*)d_in[5],
                       (const unsigned short*)d_in[6], wf);

    hipLaunchKernelGGL(aie_main, dim3(NB / 64), dim3(64), 0, stream,
                       user_rep, item_rep, wf, (float*)d_out);
}

// Round 5
// 320.868 us; speedup vs baseline: 1.4745x; 1.4745x over previous
//
#include <hip/hip_runtime.h>

#define NB 262144
#define AA 10
#define DD 10
#define KK 32

typedef unsigned int uint32;
typedef _Float16 h2 __attribute__((ext_vector_type(2)));

// ---- f16 helpers ------------------------------------------------------------
#if defined(__has_builtin)
#if __has_builtin(__builtin_amdgcn_fdot2)
#define HAVE_FDOT2 1
#endif
#endif

#ifdef HAVE_FDOT2
static __device__ __forceinline__ float fdot2(h2 a, h2 b, float c) {
    return __builtin_amdgcn_fdot2(a, b, c, false);   // v_dot2_f32_f16
}
#else
static __device__ __forceinline__ float fdot2(h2 a, h2 b, float c) {
    return fmaf((float)a.x, (float)b.x, fmaf((float)a.y, (float)b.y, c));
}
#endif

// v_cvt_pkrtz_f16_f32 returns __fp16x2; bitcast to our h2 (_Float16x2)
static __device__ __forceinline__ h2 pkrtz(float lo, float hi) {
    auto r = __builtin_amdgcn_cvt_pkrtz(lo, hi);
    union { decltype(r) a; h2 h; } c; c.a = r; return c.h;
}
static __device__ __forceinline__ h2 u2h(uint32 u) {
    union { uint32 u; h2 h; } c; c.u = u; return c.h;
}
static __device__ __forceinline__ uint32 h2u(h2 h) {
    union { uint32 u; h2 h; } c; c.h = h; return c.u;
}
static __device__ __forceinline__ h2 dup_lo(h2 x) { return __builtin_shufflevector(x, x, 0, 0); }
static __device__ __forceinline__ h2 dup_hi(h2 x) { return __builtin_shufflevector(x, x, 1, 1); }

// ---- bf16 helpers -----------------------------------------------------------
static __device__ __forceinline__ float b2f(unsigned short h) {
    union { uint32 u; float f; } c; c.u = ((uint32)h) << 16; return c.f;
}
static __device__ __forceinline__ float bflo(uint32 w) {
    union { uint32 u; float f; } c; c.u = w << 16; return c.f;
}
static __device__ __forceinline__ float bfhi(uint32 w) {
    union { uint32 u; float f; } c; c.u = w & 0xffff0000u; return c.f;
}

// f32-vs-bf16 detection by exponent-field statistics (verified earlier rounds).
__device__ __forceinline__ int detect_f32(const unsigned short* p, int nshorts,
                                          unsigned expthr, int lane) {
    int bad = 0;
    if (lane < nshorts) {
        unsigned e = (p[lane] >> 7) & 0xFFu;
        bad = (e >= expthr);
    }
    return __any(bad);
}

// ---- prep: convert + pack weights as f16 pairs into workspace ---------------
// wf layout (dwords):
//   [0:50)        Mpk[d*5+j] = {M[d][2j], M[d][2j+1]} f16x2
//   [64 +12k)     user row k: Pu[k] pairs (5) | Pi[k] pairs (5) | pu[k] f32 | pad
//   [576+12k)     item row k: Pi[k] pairs (5) | Pu[k] pairs (5) | pi[k] f32 | pad
__global__ __launch_bounds__(64) void prep_weights(
    const unsigned short* __restrict__ wM,
    const unsigned short* __restrict__ wPu,
    const unsigned short* __restrict__ wpu,
    const unsigned short* __restrict__ wPi,
    const unsigned short* __restrict__ wpi,
    uint32* __restrict__ wf)
{
    const int t = threadIdx.x;
    int f = 0;
    f |= detect_f32(wM,  64, 125, t) << 0;
    f |= detect_f32(wPu, 64, 125, t) << 1;
    f |= detect_f32(wpu, 32, 125, t) << 2;
    f |= detect_f32(wPi, 64, 125, t) << 3;
    f |= detect_f32(wpi, 32, 125, t) << 4;
    const float* fM  = (const float*)wM;
    const float* fPu = (const float*)wPu;
    const float* fpu = (const float*)wpu;
    const float* fPi = (const float*)wPi;
    const float* fpi = (const float*)wpi;

    // M pairs
    for (int i = t; i < 50; i += 64) {
        const int d = i / 5, j = i % 5;
        float a = (f & 1) ? fM[d * 10 + 2 * j]     : b2f(wM[d * 10 + 2 * j]);
        float c = (f & 1) ? fM[d * 10 + 2 * j + 1] : b2f(wM[d * 10 + 2 * j + 1]);
        wf[i] = h2u(pkrtz(a, c));
    }
    // k rows (user + item)
    for (int n = t; n < KK * 12; n += 64) {
        const int k = n / 12, j = n % 12;
        uint32 vu = 0, vi = 0;
        if (j < 5) {
            float a0 = (f & 2) ? fPu[k * 10 + 2 * j]     : b2f(wPu[k * 10 + 2 * j]);
            float a1 = (f & 2) ? fPu[k * 10 + 2 * j + 1] : b2f(wPu[k * 10 + 2 * j + 1]);
            float b0 = (f & 8) ? fPi[k * 10 + 2 * j]     : b2f(wPi[k * 10 + 2 * j]);
            float b1 = (f & 8) ? fPi[k * 10 + 2 * j + 1] : b2f(wPi[k * 10 + 2 * j + 1]);
            vu = h2u(pkrtz(a0, a1));
            vi = h2u(pkrtz(b0, b1));
        } else if (j < 10) {
            const int jj = j - 5;
            float a0 = (f & 8) ? fPi[k * 10 + 2 * jj]     : b2f(wPi[k * 10 + 2 * jj]);
            float a1 = (f & 8) ? fPi[k * 10 + 2 * jj + 1] : b2f(wPi[k * 10 + 2 * jj + 1]);
            float b0 = (f & 2) ? fPu[k * 10 + 2 * jj]     : b2f(wPu[k * 10 + 2 * jj]);
            float b1 = (f & 2) ? fPu[k * 10 + 2 * jj + 1] : b2f(wPu[k * 10 + 2 * jj + 1]);
            vu = h2u(pkrtz(a0, a1));
            vi = h2u(pkrtz(b0, b1));
        } else if (j == 10) {
            float a = (f & 4)  ? fpu[k] : b2f(wpu[k]);
            float b = (f & 16) ? fpi[k] : b2f(wpi[k]);
            union { float f; uint32 u; } ca, cb; ca.f = a; cb.f = b;
            vu = ca.u; vi = cb.u;
        }
        wf[64 + n]  = vu;
        wf[576 + n] = vi;
    }
}

// ---- input loader: one batch row (100 elems) -> 50 f16 pairs ----------------
// bf16 -> f16 is EXACT in this value range (f16 mantissa 11 > bf16's 8).
static __device__ __forceinline__ void load_rep_h(const unsigned short* __restrict__ p,
                                                  int isf32, long long b, h2 R[AA][5]) {
    if (!isf32) {
        const uint2* g = (const uint2*)(p + b * 100);
        #pragma unroll
        for (int j = 0; j < 25; j++) {
            uint2 w = g[j];
            int e = 2 * j;
            R[e / 5][e % 5]             = pkrtz(bflo(w.x), bfhi(w.x));
            R[(e + 1) / 5][(e + 1) % 5] = pkrtz(bflo(w.y), bfhi(w.y));
        }
    } else {
        const float4* g = (const float4*)((const float*)p + b * 100);
        #pragma unroll
        for (int j = 0; j < 25; j++) {
            float4 w = g[j];
            int e = 2 * j;
            R[e / 5][e % 5]             = pkrtz(w.x, w.y);
            R[(e + 1) / 5][(e + 1) % 5] = pkrtz(w.z, w.w);
        }
    }
}

// ---- main kernel -------------------------------------------------------------
// One thread per batch, ALL resident state packed f16 (Uh+Vh = 100 VGPRs).
// Round-1 dataflow (aff recomputed in item pass; no X array, no LDS at all):
//   user, per u: um = U[u]*M (pk_fma_f16, M from SGPRs);
//                per v: r = relu(dot2(um,V[v])); Wr += r*V[v]        (pk_fma)
//                k-loop: s = dot2(Pu,U[u]) + dot2(Pi,Wr); us += pu*relu(s)
//   item, per v: mv[d] = dot2(M[d],V[v]);
//                per u: r = relu(dot2(mv,U[u])); Xr += r*U[u]
//                k-loop: s = dot2(Pi,V[v]) + dot2(Pu,Xr); isc += pi*relu(s)
// Weights read with uniform indices -> s_load -> SGPR operands of VOP3P.
// Peak live ~135 regs -> 3 waves/SIMD, no AGPR copies, no scratch.
__global__ __launch_bounds__(64, 3) void aie_main(
    const unsigned short* __restrict__ user_rep,
    const unsigned short* __restrict__ item_rep,
    const uint32* __restrict__ wf,
    float* __restrict__ out)
{
    const int t = threadIdx.x;
    const long long b = (long long)blockIdx.x * 64 + t;
    const float* wff = (const float*)wf;

    const int fu = detect_f32(user_rep, 64, 137, t);
    const int fi = detect_f32(item_rep, 64, 137, t);

    h2 Uh[AA][5], Vh[AA][5];
    load_rep_h(item_rep, fi, b, Vh);
    load_rep_h(user_rep, fu, b, Uh);

    // =================== user branch ===================
    float us[AA];
    #pragma unroll
    for (int u = 0; u < AA; u++) {
        // um[j] (pairs over e) = sum_d U[u][d] * M[d][2j..2j+1]
        h2 um[5];
        {
            h2 d0 = dup_lo(Uh[u][0]);
            #pragma unroll
            for (int j = 0; j < 5; j++) um[j] = d0 * u2h(wf[j]);
        }
        #pragma unroll
        for (int d = 1; d < DD; d++) {
            h2 dd = (d & 1) ? dup_hi(Uh[u][d >> 1]) : dup_lo(Uh[u][d >> 1]);
            #pragma unroll
            for (int j = 0; j < 5; j++) um[j] += dd * u2h(wf[d * 5 + j]);
        }
        // Wr = sum_v relu(um . V[v]) * V[v]
        h2 Wr[5];
        #pragma unroll
        for (int j = 0; j < 5; j++) Wr[j] = pkrtz(0.f, 0.f);
        #pragma unroll
        for (int v = 0; v < AA; v++) {
            float r = 0.f;
            #pragma unroll
            for (int j = 0; j < 5; j++) r = fdot2(um[j], Vh[v][j], r);
            r = fmaxf(r, 0.f);
            h2 rd = pkrtz(r, r);
            #pragma unroll
            for (int j = 0; j < 5; j++) Wr[j] += rd * Vh[v][j];
        }
        // k-loop: weights via uniform s_load (SGPR operands)
        float acc = 0.f;
        #pragma unroll 2
        for (int k = 0; k < KK; k++) {
            const int o = 64 + 12 * k;
            float s = 0.f;
            #pragma unroll
            for (int j = 0; j < 5; j++) s = fdot2(u2h(wf[o + j]), Uh[u][j], s);
            #pragma unroll
            for (int j = 0; j < 5; j++) s = fdot2(u2h(wf[o + 5 + j]), Wr[j], s);
            acc += wff[o + 10] * fmaxf(s, 0.f);
        }
        us[u] = acc;
    }

    // ---- user softmax + direct stores ----
    {
        float mx = us[0];
        #pragma unroll
        for (int u = 1; u < AA; u++) mx = fmaxf(mx, us[u]);
        float s = 0.f;
        #pragma unroll
        for (int u = 0; u < AA; u++) { us[u] = __expf(us[u] - mx); s += us[u]; }
        const float inv = 1.f / s;
        float* o0 = out + b * 10;
        #pragma unroll
        for (int j = 0; j < 5; j++)
            *(float2*)(o0 + 2 * j) = make_float2(us[2 * j] * inv, us[2 * j + 1] * inv);
    }

    // =================== item branch ===================
    float isc[AA];
    #pragma unroll
    for (int v = 0; v < AA; v++) {
        // mv[d] = M[d] . V[v]  (row-dot over e), then pack pairs over d
        float mvf[DD];
        #pragma unroll
        for (int d = 0; d < DD; d++) {
            float x = 0.f;
            #pragma unroll
            for (int j = 0; j < 5; j++) x = fdot2(u2h(wf[d * 5 + j]), Vh[v][j], x);
            mvf[d] = x;
        }
        h2 mv[5];
        #pragma unroll
        for (int j = 0; j < 5; j++) mv[j] = pkrtz(mvf[2 * j], mvf[2 * j + 1]);

        // Xr = sum_u relu(U[u] . mv) * U[u]
        h2 Xr[5];
        #pragma unroll
        for (int j = 0; j < 5; j++) Xr[j] = pkrtz(0.f, 0.f);
        #pragma unroll
        for (int u = 0; u < AA; u++) {
            float r = 0.f;
            #pragma unroll
            for (int j = 0; j < 5; j++) r = fdot2(mv[j], Uh[u][j], r);
            r = fmaxf(r, 0.f);
            h2 rd = pkrtz(r, r);
            #pragma unroll
            for (int j = 0; j < 5; j++) Xr[j] += rd * Uh[u][j];
        }
        // item k-loop
        float acc = 0.f;
        #pragma unroll 2
        for (int k = 0; k < KK; k++) {
            const int o = 576 + 12 * k;
            float s = 0.f;
            #pragma unroll
            for (int j = 0; j < 5; j++) s = fdot2(u2h(wf[o + j]), Vh[v][j], s);
            #pragma unroll
            for (int j = 0; j < 5; j++) s = fdot2(u2h(wf[o + 5 + j]), Xr[j], s);
            acc += wff[o + 10] * fmaxf(s, 0.f);
        }
        isc[v] = acc;
    }

    // ---- item softmax + direct stores ----
    {
        float mx = isc[0];
        #pragma unroll
        for (int v = 1; v < AA; v++) mx = fmaxf(mx, isc[v]);
        float s = 0.f;
        #pragma unroll
        for (int v = 0; v < AA; v++) { isc[v] = __expf(isc[v] - mx); s += isc[v]; }
        const float inv = 1.f / s;
        float* o1 = out + (size_t)NB * 10 + b * 10;
        #pragma unroll
        for (int j = 0; j < 5; j++)
            *(float2*)(o1 + 2 * j) = make_float2(isc[2 * j] * inv, isc[2 * j + 1] * inv);
    }
}

extern "C" void kernel_launch(void* const* d_in, const int* in_sizes, int n_in,
                              void* d_out, int out_size, void* d_ws, size_t ws_size,
                              hipStream_t stream) {
    const unsigned short* user_rep = (const unsigned short*)d_in[0];
    const unsigned short* item_rep = (const unsigned short*)d_in[1];
    uint32* wf = (uint32*)d_ws;

    hipLaunchKernelGGL(prep_weights, dim3(1), dim3(64), 0, stream,
                       (const unsigned short*)d_in[2], (const unsigned short*)d_in[3],
                       (const unsigned short*)d_in[4], (const unsigned short*)d_in[5],
                       (const unsigned short*)d_in[6], wf);

    hipLaunchKernelGGL(aie_main, dim3(NB / 64), dim3(64), 0, stream,
                       user_rep, item_rep, wf, (float*)d_out);
}